// Round 12
// baseline (629.772 us; speedup 1.0000x reference)
//
#include <hip/hip_runtime.h>
#include <hip/hip_fp16.h>
#include <math.h>
#include <type_traits>

#define TPB  256
#define BKT  256     // dst buckets
#define CHK  256     // edge chunks
#define BCAP 12288   // padded capacity per bucket (avg 6250, >5 sigma headroom)
#define CMAX 6656    // LDS edge-chunk stage

typedef short  bf16x8 __attribute__((ext_vector_type(8)));
typedef float  f32x4  __attribute__((ext_vector_type(4)));

__device__ __forceinline__ float gelu_erf(float x){
  return 0.5f * x * (1.0f + erff(x * 0.70710678118654752440f));
}
__device__ __forceinline__ unsigned short f2bf(float f){
  union { float f; unsigned u; } v; v.f = f;
  unsigned r = v.u + 0x7fff + ((v.u >> 16) & 1);
  return (unsigned short)(r >> 16);
}
__device__ __forceinline__ float bf2f(unsigned short h){
  union { unsigned u; float f; } v; v.u = ((unsigned)h) << 16; return v.f;
}
// truncation split: f ~= bf16(h)+bf16(l), packed. Exact for fp16-sourced f.
__device__ __forceinline__ unsigned split_tr(float f){
  unsigned u = __float_as_uint(f);
  float r = f - __uint_as_float(u & 0xffff0000u);
  return (u >> 16) | (__float_as_uint(r) & 0xffff0000u);
}
__device__ __forceinline__ int divmagic(int d, unsigned long long inv){
  return (int)(((unsigned long long)(unsigned)d * inv) >> 40);
}

// ---------------- CSR build: 2 dispatches, padded buckets (R10 design) ----------------

__global__ __launch_bounds__(TPB) void prep_kernel(const int* __restrict__ src, const int* __restrict__ dst,
                                                   int* __restrict__ bcnt, int* __restrict__ bucketed,
                                                   const float* __restrict__ W0, const float* __restrict__ W1,
                                                   const float* __restrict__ W2, const float* __restrict__ W3,
                                                   unsigned short* __restrict__ Wh, unsigned short* __restrict__ Wl,
                                                   int E, int nper, unsigned long long inv){
  if (blockIdx.x < CHK){
    __shared__ int sdst[CMAX];
    __shared__ int ssrc[CMAX];
    __shared__ int lcnt[BKT];
    __shared__ int lbase[BKT];
    int m = blockIdx.x, t = threadIdx.x;
    long b0 = (long)m * E / CHK, b1 = (long)(m + 1) * E / CHK;
    for (long s0 = b0; s0 < b1; s0 += CMAX){
      int len = (int)((b1 - s0 < CMAX) ? (b1 - s0) : CMAX);
      for (int i = t; i < len; i += TPB){
        sdst[i] = __builtin_nontemporal_load(&dst[s0 + i]);
        ssrc[i] = __builtin_nontemporal_load(&src[s0 + i]);
      }
      lcnt[t] = 0;
      __syncthreads();
      for (int i = t; i < len; i += TPB) atomicAdd(&lcnt[divmagic(sdst[i], inv)], 1);
      __syncthreads();
      lbase[t] = atomicAdd(&bcnt[t], lcnt[t]);
      lcnt[t] = 0;
      __syncthreads();
      for (int i = t; i < len; i += TPB){
        int d = sdst[i];
        int b = divmagic(d, inv);
        int dl = d - b * nper;
        int r = lbase[b] + atomicAdd(&lcnt[b], 1);
        if (r < BCAP) bucketed[b * BCAP + r] = (dl << 17) | ssrc[i];
      }
      __syncthreads();
    }
  } else {
    int gid = (blockIdx.x - CHK) * TPB + threadIdx.x;
    if (gid < 3*16384){
      int which = gid >> 14, idx = gid & 16383;
      int c = idx >> 7, k = idx & 127;
      const float* W = (which == 0) ? W0 : (which == 1) ? W1 : W2;
      float f = W[k*128 + c];
      unsigned short h = f2bf(f);
      unsigned short l = f2bf(f - bf2f(h));
      Wh[gid] = h; Wl[gid] = l;
    } else if (gid < 3*16384 + 48*128){
      int idx = gid - 3*16384;
      int c = idx >> 7, k = idx & 127;
      float f = (c < 40) ? W3[k*40 + c] : 0.f;
      unsigned short h = f2bf(f);
      unsigned short l = f2bf(f - bf2f(h));
      Wh[gid] = h; Wl[gid] = l;
    }
  }
}

__global__ __launch_bounds__(TPB) void bucket_csr(const int* __restrict__ bucketed, const int* __restrict__ bcnt,
                                                  int* __restrict__ csr, int* __restrict__ row_beg,
                                                  int* __restrict__ row_end, float* __restrict__ dinv,
                                                  int N, int nper){
  int b = blockIdx.x, t = threadIdx.x;
  int base = b * BCAP;
  int nE = bcnt[b]; if (nE > BCAP) nE = BCAP;
  int nodeBase = b * nper;
  int nn = N - nodeBase; if (nn > nper) nn = nper; if (nn < 0) nn = 0;

  __shared__ int packs[BCAP];
  __shared__ int cnt[512];
  __shared__ int pref[512];

  for (int i = t; i < nn; i += TPB) cnt[i] = 0;
  __syncthreads();
  for (int i = t; i < nE; i += TPB){
    int p = bucketed[base + i];
    packs[i] = p;
    atomicAdd(&cnt[p >> 17], 1);
  }
  __syncthreads();
  if (t < 64){
    int carry = 0;
    for (int i0 = 0; i0 < nn; i0 += 64){
      int idx = i0 + t;
      int v = (idx < nn) ? cnt[idx] : 0;
      int x = v;
      #pragma unroll
      for (int off = 1; off < 64; off <<= 1){
        int y = __shfl_up(x, off);
        if (t >= off) x += y;
      }
      if (idx < nn) pref[idx] = carry + x - v;
      carry += __shfl(x, 63);
    }
  }
  __syncthreads();
  for (int i = t; i < nn; i += TPB){
    int beg = base + pref[i];
    row_beg[nodeBase + i] = beg;
    row_end[nodeBase + i] = beg + cnt[i];
    dinv[nodeBase + i] = rsqrtf((float)cnt[i] + 2.0f);
  }
  for (int i = t; i < nn; i += TPB) cnt[i] = 0;
  __syncthreads();
  for (int i = t; i < nE; i += TPB){
    int p = packs[i];
    int dl = p >> 17;
    int r = atomicAdd(&cnt[dl], 1);
    csr[base + pref[dl] + r] = p & 131071;
  }
}

// ---------------- standalone MFMA GEMM (layer 0 only: fp32 x -> xw fp16) ----------------

template<int NCT, int NC, bool BIAS, typename AT, typename CT>
__global__ __launch_bounds__(TPB) void gemm_mfma(const AT* __restrict__ A,
                                                 const unsigned short* __restrict__ Wh,
                                                 const unsigned short* __restrict__ Wl,
                                                 const float* __restrict__ bias,
                                                 CT* __restrict__ C, int n){
  constexpr int STR = NCT*16 + 8;
  __shared__ CT Cs[128][STR];
  int wave = threadIdx.x >> 6;
  int lane = threadIdx.x & 63;
  int q    = lane >> 4;
  int m16  = lane & 15;
  int rb   = blockIdx.x * 128;
  int r0   = rb + wave * 32;

  f32x4 acc[2][NCT];
  #pragma unroll
  for (int rt = 0; rt < 2; ++rt)
    #pragma unroll
    for (int ct = 0; ct < NCT; ++ct)
      acc[rt][ct] = (f32x4){0.f, 0.f, 0.f, 0.f};

  for (int k0 = 0; k0 < 128; k0 += 32){
    bf16x8 ah[2], al[2];
    #pragma unroll
    for (int rt = 0; rt < 2; ++rt){
      int r = r0 + rt*16 + m16;
      if (r > n-1) r = n-1;
      const AT* ap = A + (size_t)r*128 + k0 + q*8;
      float fv[8];
      if constexpr (std::is_same<AT, float>::value){
        float4 f0 = *(const float4*)(ap);
        float4 f1 = *(const float4*)(ap + 4);
        fv[0]=f0.x; fv[1]=f0.y; fv[2]=f0.z; fv[3]=f0.w;
        fv[4]=f1.x; fv[5]=f1.y; fv[6]=f1.z; fv[7]=f1.w;
      } else {
        uint4 u = *(const uint4*)(ap);
        const __half2* hp = (const __half2*)&u;
        #pragma unroll
        for (int i = 0; i < 4; ++i){
          float2 f = __half22float2(hp[i]);
          fv[2*i] = f.x; fv[2*i+1] = f.y;
        }
      }
      #pragma unroll
      for (int j = 0; j < 8; ++j){
        unsigned p = split_tr(fv[j]);
        ah[rt][j] = (short)(p & 0xffff);
        al[rt][j] = (short)(p >> 16);
      }
    }
    #pragma unroll
    for (int ct = 0; ct < NCT; ++ct){
      int c = ct*16 + m16;
      bf16x8 bh = *(const bf16x8*)(Wh + (size_t)c*128 + k0 + q*8);
      bf16x8 bl = *(const bf16x8*)(Wl + (size_t)c*128 + k0 + q*8);
      #pragma unroll
      for (int rt = 0; rt < 2; ++rt){
        acc[rt][ct] = __builtin_amdgcn_mfma_f32_16x16x32_bf16(ah[rt], bh, acc[rt][ct], 0, 0, 0);
        acc[rt][ct] = __builtin_amdgcn_mfma_f32_16x16x32_bf16(ah[rt], bl, acc[rt][ct], 0, 0, 0);
        acc[rt][ct] = __builtin_amdgcn_mfma_f32_16x16x32_bf16(al[rt], bh, acc[rt][ct], 0, 0, 0);
      }
    }
  }
  #pragma unroll
  for (int rt = 0; rt < 2; ++rt){
    #pragma unroll
    for (int ct = 0; ct < NCT; ++ct){
      int c = ct*16 + m16;
      if (c < NC){
        float bv = BIAS ? bias[c] : 0.f;
        #pragma unroll
        for (int i = 0; i < 4; ++i)
          Cs[wave*32 + rt*16 + q*4 + i][c] = (CT)(acc[rt][ct][i] + bv);
      }
    }
  }
  __syncthreads();
  constexpr int EPC = 16 / sizeof(CT);
  constexpr int UPR = NC / EPC;
  for (int u = threadIdx.x; u < 128 * UPR; u += TPB){
    int row = u / UPR, ch = u - row * UPR;
    int r = rb + row;
    if (r < n)
      *(uint4*)(C + (size_t)r*NC + ch*EPC) = *(const uint4*)&Cs[row][ch*EPC];
  }
}

// ---------------- standalone agg (A2 only) ----------------

template<int MODE>
__global__ __launch_bounds__(TPB) void agg_h(const __half* __restrict__ xh, const __half* __restrict__ resh,
                                             const float* __restrict__ dinv, const int* __restrict__ row_beg,
                                             const int* __restrict__ row_end, const int* __restrict__ csr_src,
                                             const float* __restrict__ bias, __half* __restrict__ outp, int n){
  int g = (int)((blockIdx.x * (unsigned)TPB + threadIdx.x) >> 4);
  if (g >= n) return;
  int lane = threadIdx.x & 15;
  float di = dinv[g];
  int beg = row_beg[g], end = row_end[g];

  float accA[8], accB[8];
  #pragma unroll
  for (int i = 0; i < 8; ++i){ accA[i] = 0.f; accB[i] = 0.f; }

  for (int base = beg; base < end; base += 16){
    int m = end - base; if (m > 16) m = 16;
    int   sl = (lane < m) ? csr_src[base + lane] : 0;
    float cl = (lane < m) ? dinv[sl] * di : 0.f;
    int mm = (m + 1) & ~1;
    for (int j = 0; j < mm; j += 2){
      int   s0 = __shfl(sl, j,   16), s1 = __shfl(sl, j+1, 16);
      float c0 = __shfl(cl, j,   16), c1 = __shfl(cl, j+1, 16);
      uint4 u0 = *(const uint4*)(xh + (size_t)s0 * 128 + lane * 8);
      uint4 u1 = *(const uint4*)(xh + (size_t)s1 * 128 + lane * 8);
      const __half2* h0 = (const __half2*)&u0;
      const __half2* h1 = (const __half2*)&u1;
      #pragma unroll
      for (int i = 0; i < 4; ++i){
        float2 f0 = __half22float2(h0[i]);
        float2 f1 = __half22float2(h1[i]);
        accA[2*i]   = fmaf(c0, f0.x, accA[2*i]);
        accA[2*i+1] = fmaf(c0, f0.y, accA[2*i+1]);
        accB[2*i]   = fmaf(c1, f1.x, accB[2*i]);
        accB[2*i+1] = fmaf(c1, f1.y, accB[2*i+1]);
      }
    }
  }
  {
    float sc = 2.0f * di * di;
    uint4 u = *(const uint4*)(xh + (size_t)g * 128 + lane * 8);
    const __half2* h = (const __half2*)&u;
    #pragma unroll
    for (int i = 0; i < 4; ++i){
      float2 f = __half22float2(h[i]);
      accA[2*i]   = fmaf(sc, f.x, accA[2*i]);
      accA[2*i+1] = fmaf(sc, f.y, accA[2*i+1]);
    }
  }
  #pragma unroll
  for (int i = 0; i < 8; ++i) accA[i] += accB[i];

  if (MODE != 2){
    float4 b0 = *(const float4*)(bias + lane*8);
    float4 b1 = *(const float4*)(bias + lane*8 + 4);
    accA[0]+=b0.x; accA[1]+=b0.y; accA[2]+=b0.z; accA[3]+=b0.w;
    accA[4]+=b1.x; accA[5]+=b1.y; accA[6]+=b1.z; accA[7]+=b1.w;
  }
  if (MODE == 1){
    uint4 ur = *(const uint4*)(resh + (size_t)g*128 + lane*8);
    const __half2* hr = (const __half2*)&ur;
    #pragma unroll
    for (int i = 0; i < 4; ++i){
      float2 f = __half22float2(hr[i]);
      accA[2*i]   += f.x;
      accA[2*i+1] += f.y;
    }
  }
  if (MODE != 2){
    #pragma unroll
    for (int i = 0; i < 8; ++i) accA[i] = gelu_erf(accA[i]);
  }
  __half hv[8];
  #pragma unroll
  for (int i = 0; i < 8; ++i) hv[i] = __float2half(accA[i]);
  *(uint4*)(outp + (size_t)g*128 + lane*8) = *(const uint4*)hv;
}

// ---------------- FUSED layer: agg(128 dst rows -> LDS A-tile [+global g]) -> MFMA xW ----------------
// Removes the g re-read by the next gemm and (for the head) the xw round-trip entirely.
// MODE: 0 gelu(agg+self+b), 1 +res, 2 plain. WRITEG: also store g to global (residual / next gather).

template<int MODE, int NCT, int NC, bool GBIAS, bool WRITEG, typename CT>
__global__ __launch_bounds__(TPB) void fused_layer(const __half* __restrict__ xh, const __half* __restrict__ resh,
                                                   const float* __restrict__ dinv, const int* __restrict__ row_beg,
                                                   const int* __restrict__ row_end, const int* __restrict__ csr_src,
                                                   const float* __restrict__ bias_agg,
                                                   const unsigned short* __restrict__ Wh,
                                                   const unsigned short* __restrict__ Wl,
                                                   const float* __restrict__ bias_gemm,
                                                   __half* __restrict__ gout, CT* __restrict__ xw_out, int n){
  constexpr int STR = NCT*16 + 8;
  __shared__ __align__(16) unsigned char ldsbuf[128*136*2];   // A-tile / Cs alias
  __half (*At)[136] = (__half(*)[136])ldsbuf;
  CT (*Cs)[STR] = (CT(*)[STR])ldsbuf;

  int rb = blockIdx.x * 128;

  // ---- agg phase: 16 groups x 16 lanes, 8 iters -> 128 rows ----
  {
    int grp  = threadIdx.x >> 4;
    int lane = threadIdx.x & 15;
    for (int it = 0; it < 8; ++it){
      int row = it*16 + grp;
      int g = rb + row;
      float accA[8];
      #pragma unroll
      for (int i = 0; i < 8; ++i) accA[i] = 0.f;
      if (g < n){
        float accB[8];
        #pragma unroll
        for (int i = 0; i < 8; ++i) accB[i] = 0.f;
        float di = dinv[g];
        int beg = row_beg[g], end = row_end[g];
        for (int base = beg; base < end; base += 16){
          int m = end - base; if (m > 16) m = 16;
          int   sl = (lane < m) ? csr_src[base + lane] : 0;
          float cl = (lane < m) ? dinv[sl] * di : 0.f;
          int mm = (m + 1) & ~1;
          for (int j = 0; j < mm; j += 2){
            int   s0 = __shfl(sl, j,   16), s1 = __shfl(sl, j+1, 16);
            float c0 = __shfl(cl, j,   16), c1 = __shfl(cl, j+1, 16);
            uint4 u0 = *(const uint4*)(xh + (size_t)s0 * 128 + lane * 8);
            uint4 u1 = *(const uint4*)(xh + (size_t)s1 * 128 + lane * 8);
            const __half2* h0 = (const __half2*)&u0;
            const __half2* h1 = (const __half2*)&u1;
            #pragma unroll
            for (int i = 0; i < 4; ++i){
              float2 f0 = __half22float2(h0[i]);
              float2 f1 = __half22float2(h1[i]);
              accA[2*i]   = fmaf(c0, f0.x, accA[2*i]);
              accA[2*i+1] = fmaf(c0, f0.y, accA[2*i+1]);
              accB[2*i]   = fmaf(c1, f1.x, accB[2*i]);
              accB[2*i+1] = fmaf(c1, f1.y, accB[2*i+1]);
            }
          }
        }
        {
          float sc = 2.0f * di * di;
          uint4 u = *(const uint4*)(xh + (size_t)g * 128 + lane * 8);
          const __half2* h = (const __half2*)&u;
          #pragma unroll
          for (int i = 0; i < 4; ++i){
            float2 f = __half22float2(h[i]);
            accA[2*i]   = fmaf(sc, f.x, accA[2*i]);
            accA[2*i+1] = fmaf(sc, f.y, accA[2*i+1]);
          }
        }
        #pragma unroll
        for (int i = 0; i < 8; ++i) accA[i] += accB[i];
        if (MODE != 2){
          float4 b0 = *(const float4*)(bias_agg + lane*8);
          float4 b1 = *(const float4*)(bias_agg + lane*8 + 4);
          accA[0]+=b0.x; accA[1]+=b0.y; accA[2]+=b0.z; accA[3]+=b0.w;
          accA[4]+=b1.x; accA[5]+=b1.y; accA[6]+=b1.z; accA[7]+=b1.w;
        }
        if (MODE == 1){
          uint4 ur = *(const uint4*)(resh + (size_t)g*128 + lane*8);
          const __half2* hr = (const __half2*)&ur;
          #pragma unroll
          for (int i = 0; i < 4; ++i){
            float2 f = __half22float2(hr[i]);
            accA[2*i]   += f.x;
            accA[2*i+1] += f.y;
          }
        }
        if (MODE != 2){
          #pragma unroll
          for (int i = 0; i < 8; ++i) accA[i] = gelu_erf(accA[i]);
        }
      }
      __half hv[8];
      #pragma unroll
      for (int i = 0; i < 8; ++i) hv[i] = __float2half(accA[i]);
      *(uint4*)&At[row][lane*8] = *(const uint4*)hv;
      if (WRITEG && g < n)
        *(uint4*)(gout + (size_t)g*128 + lane*8) = *(const uint4*)hv;
    }
  }
  __syncthreads();

  // ---- gemm phase: A from LDS ----
  int wave = threadIdx.x >> 6;
  int l64  = threadIdx.x & 63;
  int q    = l64 >> 4;
  int m16  = l64 & 15;

  f32x4 acc[2][NCT];
  #pragma unroll
  for (int rt = 0; rt < 2; ++rt)
    #pragma unroll
    for (int ct = 0; ct < NCT; ++ct)
      acc[rt][ct] = (f32x4){0.f, 0.f, 0.f, 0.f};

  for (int k0 = 0; k0 < 128; k0 += 32){
    bf16x8 ah[2], al[2];
    #pragma unroll
    for (int rt = 0; rt < 2; ++rt){
      uint4 u = *(const uint4*)&At[wave*32 + rt*16 + m16][k0 + q*8];
      const __half2* hp = (const __half2*)&u;
      #pragma unroll
      for (int i = 0; i < 4; ++i){
        float2 f = __half22float2(hp[i]);
        unsigned p0 = split_tr(f.x);
        unsigned p1 = split_tr(f.y);
        ah[rt][2*i]   = (short)(p0 & 0xffff);
        al[rt][2*i]   = (short)(p0 >> 16);
        ah[rt][2*i+1] = (short)(p1 & 0xffff);
        al[rt][2*i+1] = (short)(p1 >> 16);
      }
    }
    #pragma unroll
    for (int ct = 0; ct < NCT; ++ct){
      int c = ct*16 + m16;
      bf16x8 bh = *(const bf16x8*)(Wh + (size_t)c*128 + k0 + q*8);
      bf16x8 bl = *(const bf16x8*)(Wl + (size_t)c*128 + k0 + q*8);
      #pragma unroll
      for (int rt = 0; rt < 2; ++rt){
        acc[rt][ct] = __builtin_amdgcn_mfma_f32_16x16x32_bf16(ah[rt], bh, acc[rt][ct], 0, 0, 0);
        acc[rt][ct] = __builtin_amdgcn_mfma_f32_16x16x32_bf16(ah[rt], bl, acc[rt][ct], 0, 0, 0);
        acc[rt][ct] = __builtin_amdgcn_mfma_f32_16x16x32_bf16(al[rt], bh, acc[rt][ct], 0, 0, 0);
      }
    }
  }
  __syncthreads();   // all At reads done; ldsbuf becomes Cs
  #pragma unroll
  for (int rt = 0; rt < 2; ++rt){
    #pragma unroll
    for (int ct = 0; ct < NCT; ++ct){
      int c = ct*16 + m16;
      if (c < NC){
        float bv = GBIAS ? bias_gemm[c] : 0.f;
        #pragma unroll
        for (int i = 0; i < 4; ++i)
          Cs[wave*32 + rt*16 + q*4 + i][c] = (CT)(acc[rt][ct][i] + bv);
      }
    }
  }
  __syncthreads();
  constexpr int EPC = 16 / sizeof(CT);
  constexpr int UPR = NC / EPC;
  for (int u = threadIdx.x; u < 128 * UPR; u += TPB){
    int row = u / UPR, ch = u - row * UPR;
    int r = rb + row;
    if (r < n)
      *(uint4*)(xw_out + (size_t)r*NC + ch*EPC) = *(const uint4*)&Cs[row][ch*EPC];
  }
}

// ---------------- launch ----------------

extern "C" void kernel_launch(void* const* d_in, const int* in_sizes, int n_in,
                              void* d_out, int out_size, void* d_ws, size_t ws_size,
                              hipStream_t stream){
  const float* x  = (const float*)d_in[0];
  const int*   ei = (const int*)d_in[1];
  const float* W0 = (const float*)d_in[2];
  const float* b0 = (const float*)d_in[3];
  const float* W1 = (const float*)d_in[4];
  const float* b1 = (const float*)d_in[5];
  const float* W2 = (const float*)d_in[6];
  const float* b2 = (const float*)d_in[7];
  const float* W3 = (const float*)d_in[8];
  const float* b3 = (const float*)d_in[9];
  float* out = (float*)d_out;

  const int N = in_sizes[0] / 128;
  const int E = in_sizes[1] / 2;
  const int* src = ei;
  const int* dst = ei + E;
  const int nper = (N + BKT - 1) / BKT;   // 391
  const unsigned long long inv = ((1ULL << 40) + nper - 1) / (unsigned long long)nper;

  char* ws = (char*)d_ws;
  size_t off = 0;
  auto alloc = [&](size_t bytes) -> void* {
    void* p = ws + off;
    off += (bytes + 255) & ~(size_t)255;
    return p;
  };
  __half* xwA   = (__half*)alloc((size_t)N * 128 * 2);
  __half* xwB   = (__half*)alloc((size_t)N * 128 * 2);
  __half* g0    = (__half*)alloc((size_t)N * 128 * 2);
  __half* g1    = (__half*)alloc((size_t)N * 128 * 2);
  __half* g2    = (__half*)alloc((size_t)N * 128 * 2);
  int* csr      = (int*)   alloc((size_t)BKT * BCAP * 4);
  int* bucketed = (int*)   alloc((size_t)BKT * BCAP * 4);
  int* row_beg  = (int*)   alloc((size_t)N * 4);
  int* row_end  = (int*)   alloc((size_t)N * 4);
  float* dnv    = (float*) alloc((size_t)N * 4);
  int* bcnt     = (int*)   alloc((size_t)BKT * 4);
  const int WTOT = 3*16384 + 48*128;
  unsigned short* Wh = (unsigned short*)alloc((size_t)WTOT * 2);
  unsigned short* Wl = (unsigned short*)alloc((size_t)WTOT * 2);
  (void)ws_size; (void)n_in; (void)out_size;

  (void)hipMemsetAsync(bcnt, 0, (size_t)BKT * 4, stream);
  const int WB = (WTOT + TPB - 1) / TPB;
  prep_kernel<<<CHK + WB, TPB, 0, stream>>>(src, dst, bcnt, bucketed, W0, W1, W2, W3, Wh, Wl, E, nper, inv);
  bucket_csr<<<BKT, TPB, 0, stream>>>(bucketed, bcnt, csr, row_beg, row_end, dnv, N, nper);

  int gblocks = (N + 127) / 128;
  int ablocks = ((size_t)N * 16 + TPB - 1) / TPB;

  const unsigned short* W0h = Wh,          *W0l = Wl;
  const unsigned short* W1h = Wh + 16384,  *W1l = Wl + 16384;
  const unsigned short* W2h = Wh + 32768,  *W2l = Wl + 32768;
  const unsigned short* W3h = Wh + 49152,  *W3l = Wl + 49152;

  // G0: xwA = x @ W0
  gemm_mfma<8,128,false,float,__half><<<gblocks, TPB, 0, stream>>>(x, W0h, W0l, nullptr, xwA, N);
  // F1: g0 = gelu(Agg(xwA)+b0);  xwB = g0 @ W1
  fused_layer<0,8,128,false,true,__half><<<gblocks, TPB, 0, stream>>>(
      xwA, nullptr, dnv, row_beg, row_end, csr, b0, W1h, W1l, nullptr, g0, xwB, N);
  // F2: g1 = gelu(Agg(xwB)+b1+g0);  xwA = g1 @ W2
  fused_layer<1,8,128,false,true,__half><<<gblocks, TPB, 0, stream>>>(
      xwB, g0, dnv, row_beg, row_end, csr, b1, W2h, W2l, nullptr, g1, xwA, N);
  // A2: g2 = gelu(Agg(xwA)+b2+g1)   (cannot fuse forward: A3 gathers from all of g2)
  agg_h<1><<<ablocks, TPB, 0, stream>>>(xwA, g1, dnv, row_beg, row_end, csr, b2, g2, N);
  // F3: out = Agg(g2) @ W3 + b3   (agg result lives only in LDS)
  fused_layer<2,3,40,true,false,float><<<gblocks, TPB, 0, stream>>>(
      g2, nullptr, dnv, row_beg, row_end, csr, nullptr, W3h, W3l, b3, nullptr, out, N);
}